// Round 4
// baseline (906.537 us; speedup 1.0000x reference)
//
#include <hip/hip_runtime.h>

// GraphVAE on MI355X — all tensors float32 (per reference), edge_index int32.
// pseudo == 0  =>  degree-1 spline basis selects kernel 0 only  =>
//   spline_conv(x) = scatter_mean(x[src], dst) @ W[0] + x @ root + b
// Linearity: aggregate raw feature rows first, then one small GEMM per conv.
//
// Workspace (f32): deg[N] | S1[N*64] (reused as S2) | h[N*64]  = N*129 floats.

#define IN 64
#define HID 64
#define LAT 32

// ---------------- scatter-add of x rows + degree ----------------
__global__ __launch_bounds__(256) void k_scatter_x(
    const float* __restrict__ x, const int* __restrict__ ei,
    float* __restrict__ S1, float* __restrict__ deg, int E) {
  int t = blockIdx.x * 256 + threadIdx.x;
  int e = t >> 6;
  if (e >= E) return;
  int lane = t & 63;
  int src = ei[e];
  int dst = ei[E + e];
  float v = x[(size_t)src * 64 + lane];
  atomicAdd(&S1[(size_t)dst * 64 + lane], v);
  if (lane == 0) atomicAdd(&deg[dst], 1.0f);
}

// ---------------- scatter-add of h rows ----------------
__global__ __launch_bounds__(256) void k_scatter_h(
    const float* __restrict__ h, const int* __restrict__ ei,
    float* __restrict__ S2, int E) {
  int t = blockIdx.x * 256 + threadIdx.x;
  int e = t >> 6;
  if (e >= E) return;
  int lane = t & 63;
  int src = ei[e];
  int dst = ei[E + e];
  float v = h[(size_t)src * 64 + lane];
  atomicAdd(&S2[(size_t)dst * 64 + lane], v);
}

// ---------------- conv1: h = relu((S1/deg) @ w1[0] + x @ root1 + b1) ----------------
__global__ __launch_bounds__(256) void k_conv1(
    const float* __restrict__ S1, const float* __restrict__ deg,
    const float* __restrict__ x,
    const float* __restrict__ w1, const float* __restrict__ root1,
    const float* __restrict__ b1,
    float* __restrict__ h, int N) {
  __shared__ float W[64][64];   // w1[0] : [IN][HID]
  __shared__ float R[64][64];   // root1 : [IN][HID]
  __shared__ float B[64];
  for (int i = threadIdx.x; i < 64 * 64; i += 256) {
    W[i >> 6][i & 63] = w1[i];       // first K-slice of w1
    R[i >> 6][i & 63] = root1[i];
  }
  if (threadIdx.x < 64) B[threadIdx.x] = b1[threadIdx.x];
  __syncthreads();

  int n = blockIdx.x * 4 + (threadIdx.x >> 6);
  if (n >= N) return;
  int lane = threadIdx.x & 63;

  float invd = 1.0f / fmaxf(deg[n], 1.0f);
  float a = S1[(size_t)n * 64 + lane] * invd;   // A1[n][lane]
  float xv = x[(size_t)n * 64 + lane];          // x[n][lane]

  float acc = B[lane];
  #pragma unroll
  for (int i = 0; i < 64; ++i) {
    float ai = __shfl(a, i);
    float xi = __shfl(xv, i);
    acc = fmaf(ai, W[i][lane], acc);
    acc = fmaf(xi, R[i][lane], acc);
  }
  h[(size_t)n * 64 + lane] = fmaxf(acc, 0.0f);
}

// ---------------- decode: mu/logvar + reparam + fc1 + fc2 ----------------
__global__ __launch_bounds__(256) void k_decode(
    const float* __restrict__ S2, const float* __restrict__ deg,
    const float* __restrict__ h, const float* __restrict__ eps,
    const float* __restrict__ w_mu, const float* __restrict__ root_mu,
    const float* __restrict__ b_mu,
    const float* __restrict__ w_lv, const float* __restrict__ root_lv,
    const float* __restrict__ b_lv,
    const float* __restrict__ fc1_w, const float* __restrict__ fc1_b,
    const float* __restrict__ fc2_w, const float* __restrict__ fc2_b,
    float* __restrict__ out, int N) {
  __shared__ float Wm[64][32], Rm[64][32];   // w_mu[0], root_mu
  __shared__ float Wl[64][32], Rl[64][32];   // w_lv[0], root_lv
  __shared__ float F1[32][64];               // fc1_w [LAT][HID]
  __shared__ float F2[64][64];               // fc2_w [HID][IN]
  __shared__ float Bm[32], Bl[32], B1[64], B2[64];

  for (int i = threadIdx.x; i < 64 * 32; i += 256) {
    Wm[i >> 5][i & 31] = w_mu[i];      // first K-slice of w_mu
    Rm[i >> 5][i & 31] = root_mu[i];
    Wl[i >> 5][i & 31] = w_lv[i];      // first K-slice of w_lv
    Rl[i >> 5][i & 31] = root_lv[i];
  }
  for (int i = threadIdx.x; i < 32 * 64; i += 256) F1[i >> 6][i & 63] = fc1_w[i];
  for (int i = threadIdx.x; i < 64 * 64; i += 256) F2[i >> 6][i & 63] = fc2_w[i];
  if (threadIdx.x < 32) {
    Bm[threadIdx.x] = b_mu[threadIdx.x];
    Bl[threadIdx.x] = b_lv[threadIdx.x];
  }
  if (threadIdx.x < 64) {
    B1[threadIdx.x] = fc1_b[threadIdx.x];
    B2[threadIdx.x] = fc2_b[threadIdx.x];
  }
  __syncthreads();

  int n = blockIdx.x * 4 + (threadIdx.x >> 6);
  if (n >= N) return;
  int lane = threadIdx.x & 63;
  int j = lane & 31;
  bool isMu = lane < 32;

  float invd = 1.0f / fmaxf(deg[n], 1.0f);
  float a = S2[(size_t)n * 64 + lane] * invd;   // A2[n][lane]
  float hv = h[(size_t)n * 64 + lane];          // h[n][lane]

  // Stage A: lanes 0..31 -> mu[j], lanes 32..63 -> logvar[j]
  const float (*Wp)[32] = isMu ? Wm : Wl;
  const float (*Rp)[32] = isMu ? Rm : Rl;
  float acc = isMu ? Bm[j] : Bl[j];
  #pragma unroll
  for (int i = 0; i < 64; ++i) {
    float ai = __shfl(a, i);
    float hi = __shfl(hv, i);
    acc = fmaf(ai, Wp[i][j], acc);
    acc = fmaf(hi, Rp[i][j], acc);
  }
  // out layout: recon[N*64] | mu[N*32] | logvar[N*32]
  size_t Ns = (size_t)N;
  if (isMu) out[Ns * 64 + (size_t)n * 32 + j] = acc;
  else      out[Ns * 96 + (size_t)n * 32 + j] = acc;

  // reparameterize: every lane computes z[j] (duplicated across halves)
  float mu_j = __shfl(acc, j);
  float lv_j = __shfl(acc, j + 32);
  float ev = eps[(size_t)n * 32 + j];
  float z = mu_j + ev * expf(0.5f * lv_j);

  // Stage B: hd[lane] = relu(sum_j z[j]*F1[j][lane] + B1[lane])
  float hd = B1[lane];
  #pragma unroll
  for (int jj = 0; jj < 32; ++jj) {
    float zj = __shfl(z, jj);
    hd = fmaf(zj, F1[jj][lane], hd);
  }
  hd = fmaxf(hd, 0.0f);

  // Stage C: recon[lane] = sum_k hd[k]*F2[k][lane] + B2[lane]
  float rc = B2[lane];
  #pragma unroll
  for (int k = 0; k < 64; ++k) {
    float hk = __shfl(hd, k);
    rc = fmaf(hk, F2[k][lane], rc);
  }
  out[(size_t)n * 64 + lane] = rc;
}

extern "C" void kernel_launch(void* const* d_in, const int* in_sizes, int n_in,
                              void* d_out, int out_size, void* d_ws, size_t ws_size,
                              hipStream_t stream) {
  const float* x       = (const float*)d_in[0];
  const int*   ei      = (const int*)d_in[1];
  const float* eps     = (const float*)d_in[2];
  const float* w1      = (const float*)d_in[3];
  const float* root1   = (const float*)d_in[4];
  const float* b1      = (const float*)d_in[5];
  const float* w_mu    = (const float*)d_in[6];
  const float* root_mu = (const float*)d_in[7];
  const float* b_mu    = (const float*)d_in[8];
  const float* w_lv    = (const float*)d_in[9];
  const float* root_lv = (const float*)d_in[10];
  const float* b_lv    = (const float*)d_in[11];
  const float* fc1_w   = (const float*)d_in[12];
  const float* fc1_b   = (const float*)d_in[13];
  const float* fc2_w   = (const float*)d_in[14];
  const float* fc2_b   = (const float*)d_in[15];

  const int N = in_sizes[0] / 64;   // 50000
  const int E = in_sizes[1] / 2;    // 800000

  // workspace layout (f32): deg[N] | S1[N*64] (reused as S2) | h[N*64]
  float* deg = (float*)d_ws;
  float* S1  = deg + N;
  float* h   = S1 + (size_t)N * 64;
  float* S2  = S1;   // reuse after conv1 consumes S1

  int scatter_blocks = (E * 64 + 255) / 256;

  // zero deg + S1 (contiguous N*65 floats)
  hipMemsetAsync(deg, 0, sizeof(float) * (size_t)N * 65, stream);
  k_scatter_x<<<scatter_blocks, 256, 0, stream>>>(x, ei, S1, deg, E);
  k_conv1<<<(N + 3) / 4, 256, 0, stream>>>(S1, deg, x, w1, root1, b1, h, N);
  // re-zero S1 to serve as S2
  hipMemsetAsync(S2, 0, sizeof(float) * (size_t)N * 64, stream);
  k_scatter_h<<<scatter_blocks, 256, 0, stream>>>(h, ei, S2, E);
  k_decode<<<(N + 3) / 4, 256, 0, stream>>>(S2, deg, h, eps,
      w_mu, root_mu, b_mu, w_lv, root_lv, b_lv,
      fc1_w, fc1_b, fc2_w, fc2_b, (float*)d_out, N);
}